// Round 1
// baseline (690.803 us; speedup 1.0000x reference)
//
#include <hip/hip_runtime.h>
#include <hip/hip_bf16.h>
#include <math.h>

#define N_NODES 50000
#define N_EDGES 800000
#define IN_DIM 256
#define HID 32
#define HEADS 4
#define OUT_DIM 64

#define SCAN_CHUNK 1024
#define SCAN_BLOCKS ((N_NODES + SCAN_CHUNK - 1) / SCAN_CHUNK)  // 49

// ---------------- CSR build (by dst) ----------------

__global__ void hist_kernel(const int* __restrict__ dst, int* __restrict__ count) {
    int i = blockIdx.x * blockDim.x + threadIdx.x;
    if (i < N_EDGES) atomicAdd(&count[dst[i]], 1);
}

__global__ void scan1_kernel(const int* __restrict__ count, int* __restrict__ row_start,
                             int* __restrict__ blocksum) {
    __shared__ int sdata[256];
    int t = threadIdx.x;
    int base = blockIdx.x * SCAN_CHUNK + t * 4;
    int v[4];
    int s = 0;
#pragma unroll
    for (int j = 0; j < 4; j++) {
        int idx = base + j;
        int x = (idx < N_NODES) ? count[idx] : 0;
        v[j] = x;
        s += x;
    }
    sdata[t] = s;
    __syncthreads();
    for (int off = 1; off < 256; off <<= 1) {
        int u = (t >= off) ? sdata[t - off] : 0;
        __syncthreads();
        sdata[t] += u;
        __syncthreads();
    }
    int excl = sdata[t] - s;
#pragma unroll
    for (int j = 0; j < 4; j++) {
        int idx = base + j;
        if (idx < N_NODES) row_start[idx] = excl;
        excl += v[j];
    }
    if (t == 255) blocksum[blockIdx.x] = sdata[255];
}

__global__ void scan2_kernel(const int* __restrict__ blocksum, int* __restrict__ bs2) {
    int t = threadIdx.x;  // 64 threads, one wave
    int v = (t < SCAN_BLOCKS) ? blocksum[t] : 0;
    int orig = v;
#pragma unroll
    for (int off = 1; off < 64; off <<= 1) {
        int u = __shfl_up(v, off);
        if (t >= off) v += u;
    }
    if (t < SCAN_BLOCKS) bs2[t] = v - orig;
}

__global__ void scan3_kernel(int* __restrict__ row_start, const int* __restrict__ bs2,
                             int* __restrict__ cursor) {
    int t = threadIdx.x;
    int add = bs2[blockIdx.x];
    int base = blockIdx.x * SCAN_CHUNK + t * 4;
#pragma unroll
    for (int j = 0; j < 4; j++) {
        int idx = base + j;
        if (idx < N_NODES) {
            int r = row_start[idx] + add;
            row_start[idx] = r;
            cursor[idx] = r;
        }
    }
}

__global__ void scatter_kernel(const int* __restrict__ src, const int* __restrict__ dst,
                               int* __restrict__ cursor, int* __restrict__ esrc) {
    int i = blockIdx.x * blockDim.x + threadIdx.x;
    if (i < N_EDGES) {
        int d = dst[i];
        int pos = atomicAdd(&cursor[d], 1);
        esrc[pos] = src[i];
    }
}

// ---------------- Layer 1 projection: z1 = h @ W1, es1/ed1 logits ----------------
// block = 128 threads (4 heads x 32), one node per block

__global__ void proj1_kernel(const float* __restrict__ h, const float* __restrict__ W1,
                             const float* __restrict__ a1, float* __restrict__ z1,
                             float* __restrict__ es1, float* __restrict__ ed1) {
    __shared__ __align__(16) float hs[IN_DIM];
    int n = blockIdx.x;
    int t = threadIdx.x;
    for (int i = t; i < IN_DIM; i += 128) hs[i] = h[n * IN_DIM + i];
    __syncthreads();
    int hd = t >> 5, o = t & 31;
    const float* Wp = W1 + (hd * IN_DIM) * HID + o;
    float acc = 0.f;
    for (int k = 0; k < IN_DIM; k += 4) {
        float4 hv = *(const float4*)&hs[k];
        acc += hv.x * Wp[(k + 0) * HID];
        acc += hv.y * Wp[(k + 1) * HID];
        acc += hv.z * Wp[(k + 2) * HID];
        acc += hv.w * Wp[(k + 3) * HID];
    }
    z1[n * 128 + t] = acc;
    float es = acc * a1[hd * 2 * HID + o];
    float ed = acc * a1[hd * 2 * HID + HID + o];
#pragma unroll
    for (int off = 16; off >= 1; off >>= 1) {
        es += __shfl_xor(es, off);
        ed += __shfl_xor(ed, off);
    }
    if (o == 0) {
        es1[n * HEADS + hd] = es;
        ed1[n * HEADS + hd] = ed;
    }
}

// ---------------- Layer 1 aggregation + ELU ----------------
// block = 128 threads (4 heads x 32 lanes), one dst node per block

__global__ void agg1_kernel(const float* __restrict__ z1, const float* __restrict__ es1,
                            const float* __restrict__ ed1, const int* __restrict__ row_start,
                            const int* __restrict__ count, const int* __restrict__ esrc,
                            float* __restrict__ h1) {
    int v = blockIdx.x;
    int t = threadIdx.x;
    int hd = t >> 5, o = t & 31;
    int beg = row_start[v], deg = count[v];
    float edv = ed1[v * HEADS + hd];
    float m = -1e30f;
    for (int j = 0; j < deg; j++) {
        int s = esrc[beg + j];
        float e = es1[s * HEADS + hd] + edv;
        e = e > 0.f ? e : 0.01f * e;  // leaky_relu(0.01)
        m = fmaxf(m, e);
    }
    float l = 0.f, acc = 0.f;
    for (int j = 0; j < deg; j++) {
        int s = esrc[beg + j];
        float e = es1[s * HEADS + hd] + edv;
        e = e > 0.f ? e : 0.01f * e;
        float p = __expf(e - m);
        l += p;
        acc += p * z1[s * 128 + hd * HID + o];
    }
    float r = (deg > 0) ? acc / l : 0.f;
    r = r > 0.f ? r : expm1f(r);  // elu
    h1[v * 128 + t] = r;
}

// ---------------- Layer 2 projection: z2 = h1 @ W2, es2/ed2 ----------------
// block = 64 threads, one node per block

__global__ void proj2_kernel(const float* __restrict__ h1, const float* __restrict__ W2,
                             const float* __restrict__ a2, float* __restrict__ z2,
                             float* __restrict__ es2, float* __restrict__ ed2) {
    __shared__ __align__(16) float hs[128];
    int n = blockIdx.x, t = threadIdx.x;
    for (int i = t; i < 128; i += 64) hs[i] = h1[n * 128 + i];
    __syncthreads();
    const float* Wp = W2 + t;
    float acc = 0.f;
    for (int k = 0; k < 128; k += 4) {
        float4 hv = *(const float4*)&hs[k];
        acc += hv.x * Wp[(k + 0) * OUT_DIM];
        acc += hv.y * Wp[(k + 1) * OUT_DIM];
        acc += hv.z * Wp[(k + 2) * OUT_DIM];
        acc += hv.w * Wp[(k + 3) * OUT_DIM];
    }
    z2[n * OUT_DIM + t] = acc;
    float es = acc * a2[t];
    float ed = acc * a2[OUT_DIM + t];
#pragma unroll
    for (int off = 32; off >= 1; off >>= 1) {
        es += __shfl_xor(es, off);
        ed += __shfl_xor(ed, off);
    }
    if (t == 0) {
        es2[n] = es;
        ed2[n] = ed;
    }
}

// ---------------- Layer 2 aggregation (final output) ----------------
// block = 64 threads (1 head x 64 lanes), one dst node per block

__global__ void agg2_kernel(const float* __restrict__ z2, const float* __restrict__ es2,
                            const float* __restrict__ ed2, const int* __restrict__ row_start,
                            const int* __restrict__ count, const int* __restrict__ esrc,
                            float* __restrict__ out) {
    int v = blockIdx.x, t = threadIdx.x;
    int beg = row_start[v], deg = count[v];
    float edv = ed2[v];
    float m = -1e30f;
    for (int j = 0; j < deg; j++) {
        int s = esrc[beg + j];
        float e = es2[s] + edv;
        e = e > 0.f ? e : 0.01f * e;
        m = fmaxf(m, e);
    }
    float l = 0.f, acc = 0.f;
    for (int j = 0; j < deg; j++) {
        int s = esrc[beg + j];
        float e = es2[s] + edv;
        e = e > 0.f ? e : 0.01f * e;
        float p = __expf(e - m);
        l += p;
        acc += p * z2[s * OUT_DIM + t];
    }
    out[v * OUT_DIM + t] = (deg > 0) ? acc / l : 0.f;
}

// ---------------- launch ----------------

extern "C" void kernel_launch(void* const* d_in, const int* in_sizes, int n_in,
                              void* d_out, int out_size, void* d_ws, size_t ws_size,
                              hipStream_t stream) {
    const float* h  = (const float*)d_in[0];
    const int* src  = (const int*)d_in[1];
    const int* dst  = (const int*)d_in[2];
    const float* W1 = (const float*)d_in[3];
    const float* a1 = (const float*)d_in[4];
    const float* W2 = (const float*)d_in[5];
    const float* a2 = (const float*)d_in[6];
    float* out = (float*)d_out;

    char* w = (char*)d_ws;
    size_t off = 0;
    auto alloc = [&](size_t bytes) {
        void* p = w + off;
        off = (off + bytes + 255) & ~(size_t)255;
        return p;
    };
    float* z1  = (float*)alloc((size_t)N_NODES * 128 * 4);
    float* es1 = (float*)alloc((size_t)N_NODES * HEADS * 4);
    float* ed1 = (float*)alloc((size_t)N_NODES * HEADS * 4);
    float* h1  = (float*)alloc((size_t)N_NODES * 128 * 4);
    float* z2  = (float*)alloc((size_t)N_NODES * OUT_DIM * 4);
    float* es2 = (float*)alloc((size_t)N_NODES * 4);
    float* ed2 = (float*)alloc((size_t)N_NODES * 4);
    int* count     = (int*)alloc((size_t)N_NODES * 4);
    int* row_start = (int*)alloc((size_t)N_NODES * 4);
    int* cursor    = (int*)alloc((size_t)N_NODES * 4);
    int* blocksum  = (int*)alloc((size_t)SCAN_BLOCKS * 4);
    int* bs2       = (int*)alloc((size_t)SCAN_BLOCKS * 4);
    int* esrc      = (int*)alloc((size_t)N_EDGES * 4);

    hipMemsetAsync(count, 0, (size_t)N_NODES * 4, stream);
    hist_kernel<<<(N_EDGES + 255) / 256, 256, 0, stream>>>(dst, count);
    scan1_kernel<<<SCAN_BLOCKS, 256, 0, stream>>>(count, row_start, blocksum);
    scan2_kernel<<<1, 64, 0, stream>>>(blocksum, bs2);
    scan3_kernel<<<SCAN_BLOCKS, 256, 0, stream>>>(row_start, bs2, cursor);
    scatter_kernel<<<(N_EDGES + 255) / 256, 256, 0, stream>>>(src, dst, cursor, esrc);

    proj1_kernel<<<N_NODES, 128, 0, stream>>>(h, W1, a1, z1, es1, ed1);
    agg1_kernel<<<N_NODES, 128, 0, stream>>>(z1, es1, ed1, row_start, count, esrc, h1);
    proj2_kernel<<<N_NODES, 64, 0, stream>>>(h1, W2, a2, z2, es2, ed2);
    agg2_kernel<<<N_NODES, 64, 0, stream>>>(z2, es2, ed2, row_start, count, esrc, out);
}

// Round 2
// 587.416 us; speedup vs baseline: 1.1760x; 1.1760x over previous
//
#include <hip/hip_runtime.h>
#include <hip/hip_bf16.h>
#include <math.h>

#define N_NODES 50000
#define N_EDGES 800000
#define IN_DIM 256
#define HID 32
#define HEADS 4
#define OUT_DIM 64

#define SCAN_CHUNK 1024
#define SCAN_BLOCKS ((N_NODES + SCAN_CHUNK - 1) / SCAN_CHUNK)  // 49

// ---------------- CSR build (by dst) ----------------

__global__ void hist_kernel(const int* __restrict__ dst, int* __restrict__ count) {
    int i = blockIdx.x * blockDim.x + threadIdx.x;
    if (i < N_EDGES) atomicAdd(&count[dst[i]], 1);
}

__global__ void scan1_kernel(const int* __restrict__ count, int* __restrict__ row_start,
                             int* __restrict__ blocksum) {
    __shared__ int sdata[256];
    int t = threadIdx.x;
    int base = blockIdx.x * SCAN_CHUNK + t * 4;
    int v[4];
    int s = 0;
#pragma unroll
    for (int j = 0; j < 4; j++) {
        int idx = base + j;
        int x = (idx < N_NODES) ? count[idx] : 0;
        v[j] = x;
        s += x;
    }
    sdata[t] = s;
    __syncthreads();
    for (int off = 1; off < 256; off <<= 1) {
        int u = (t >= off) ? sdata[t - off] : 0;
        __syncthreads();
        sdata[t] += u;
        __syncthreads();
    }
    int excl = sdata[t] - s;
#pragma unroll
    for (int j = 0; j < 4; j++) {
        int idx = base + j;
        if (idx < N_NODES) row_start[idx] = excl;
        excl += v[j];
    }
    if (t == 255) blocksum[blockIdx.x] = sdata[255];
}

__global__ void scan2_kernel(const int* __restrict__ blocksum, int* __restrict__ bs2) {
    int t = threadIdx.x;  // 64 threads, one wave
    int v = (t < SCAN_BLOCKS) ? blocksum[t] : 0;
    int orig = v;
#pragma unroll
    for (int off = 1; off < 64; off <<= 1) {
        int u = __shfl_up(v, off);
        if (t >= off) v += u;
    }
    if (t < SCAN_BLOCKS) bs2[t] = v - orig;
}

__global__ void scan3_kernel(int* __restrict__ row_start, const int* __restrict__ bs2,
                             int* __restrict__ cursor) {
    int t = threadIdx.x;
    int add = bs2[blockIdx.x];
    int base = blockIdx.x * SCAN_CHUNK + t * 4;
#pragma unroll
    for (int j = 0; j < 4; j++) {
        int idx = base + j;
        if (idx < N_NODES) {
            int r = row_start[idx] + add;
            row_start[idx] = r;
            cursor[idx] = r;
        }
    }
}

__global__ void scatter_kernel(const int* __restrict__ src, const int* __restrict__ dst,
                               int* __restrict__ cursor, int* __restrict__ esrc) {
    int i = blockIdx.x * blockDim.x + threadIdx.x;
    if (i < N_EDGES) {
        int d = dst[i];
        int pos = atomicAdd(&cursor[d], 1);
        esrc[pos] = src[i];
    }
}

// ---------------- Layer 1 projection: z1 = h @ W1, es1/ed1 logits ----------------
// Register-blocked GEMM: block = 128 threads (thread t owns output col t),
// NB=16 nodes per block. W chunk (32 k-values) held in VGPRs, amortized over
// 16 nodes; h read via same-address broadcast ds_read_b128 (1 LDS instr / 4 FMA).

#define NB1 16

__global__ void __launch_bounds__(128) proj1_kernel(
        const float* __restrict__ h, const float* __restrict__ W1,
        const float* __restrict__ a1, float* __restrict__ z1,
        float* __restrict__ es1, float* __restrict__ ed1) {
    __shared__ __align__(16) float hs[NB1][IN_DIM];  // 16 KB
    int t = threadIdx.x;
    int n0 = blockIdx.x * NB1;
    // stage 16 h rows, fully coalesced float4
    {
        const float4* src4 = (const float4*)(h + (size_t)n0 * IN_DIM);
        float4* dst4 = (float4*)&hs[0][0];
        for (int i = t; i < NB1 * IN_DIM / 4; i += 128) dst4[i] = src4[i];
    }
    __syncthreads();

    int hd = t >> 5, o = t & 31;
    float acc[NB1];
#pragma unroll
    for (int n = 0; n < NB1; n++) acc[n] = 0.f;

    const float* Wbase = W1 + (size_t)hd * IN_DIM * HID + o;
#pragma unroll 1
    for (int k0 = 0; k0 < IN_DIM; k0 += 32) {
        float w[32];
#pragma unroll
        for (int j = 0; j < 32; j++) w[j] = Wbase[(size_t)(k0 + j) * HID];
#pragma unroll
        for (int n = 0; n < NB1; n++) {
#pragma unroll
            for (int j = 0; j < 32; j += 4) {
                float4 hv = *(const float4*)&hs[n][k0 + j];  // broadcast read
                acc[n] = fmaf(hv.x, w[j + 0], acc[n]);
                acc[n] = fmaf(hv.y, w[j + 1], acc[n]);
                acc[n] = fmaf(hv.z, w[j + 2], acc[n]);
                acc[n] = fmaf(hv.w, w[j + 3], acc[n]);
            }
        }
    }

    float asv = a1[hd * 2 * HID + o];
    float adv = a1[hd * 2 * HID + HID + o];
#pragma unroll
    for (int n = 0; n < NB1; n++) {
        float z = acc[n];
        z1[(size_t)(n0 + n) * 128 + t] = z;
        float es = z * asv;
        float ed = z * adv;
#pragma unroll
        for (int off = 16; off >= 1; off >>= 1) {
            es += __shfl_xor(es, off);
            ed += __shfl_xor(ed, off);
        }
        if (o == 0) {
            es1[(n0 + n) * HEADS + hd] = es;
            ed1[(n0 + n) * HEADS + hd] = ed;
        }
    }
}

// ---------------- Layer 1 aggregation + ELU ----------------
// block = 128 threads (4 heads x 32 lanes), one dst node per block

__global__ void agg1_kernel(const float* __restrict__ z1, const float* __restrict__ es1,
                            const float* __restrict__ ed1, const int* __restrict__ row_start,
                            const int* __restrict__ count, const int* __restrict__ esrc,
                            float* __restrict__ h1) {
    int v = blockIdx.x;
    int t = threadIdx.x;
    int hd = t >> 5, o = t & 31;
    int beg = row_start[v], deg = count[v];
    float edv = ed1[v * HEADS + hd];
    float m = -1e30f;
    for (int j = 0; j < deg; j++) {
        int s = esrc[beg + j];
        float e = es1[s * HEADS + hd] + edv;
        e = e > 0.f ? e : 0.01f * e;  // leaky_relu(0.01)
        m = fmaxf(m, e);
    }
    float l = 0.f, acc = 0.f;
    for (int j = 0; j < deg; j++) {
        int s = esrc[beg + j];
        float e = es1[s * HEADS + hd] + edv;
        e = e > 0.f ? e : 0.01f * e;
        float p = __expf(e - m);
        l += p;
        acc += p * z1[s * 128 + hd * HID + o];
    }
    float r = (deg > 0) ? acc / l : 0.f;
    r = r > 0.f ? r : expm1f(r);  // elu
    h1[v * 128 + t] = r;
}

// ---------------- Layer 2 projection: z2 = h1 @ W2, es2/ed2 ----------------
// Same register-blocked structure: block = 64 threads (one per output col),
// NB=16 nodes, W2 is 32 KB -> L1-resident.

#define NB2 16

__global__ void __launch_bounds__(64) proj2_kernel(
        const float* __restrict__ h1, const float* __restrict__ W2,
        const float* __restrict__ a2, float* __restrict__ z2,
        float* __restrict__ es2, float* __restrict__ ed2) {
    __shared__ __align__(16) float hs[NB2][128];  // 8 KB
    int t = threadIdx.x;  // 0..63, one wave
    int n0 = blockIdx.x * NB2;
    {
        const float4* src4 = (const float4*)(h1 + (size_t)n0 * 128);
        float4* dst4 = (float4*)&hs[0][0];
        for (int i = t; i < NB2 * 128 / 4; i += 64) dst4[i] = src4[i];
    }
    __syncthreads();

    float acc[NB2];
#pragma unroll
    for (int n = 0; n < NB2; n++) acc[n] = 0.f;

    const float* Wbase = W2 + t;
#pragma unroll 1
    for (int k0 = 0; k0 < 128; k0 += 32) {
        float w[32];
#pragma unroll
        for (int j = 0; j < 32; j++) w[j] = Wbase[(size_t)(k0 + j) * OUT_DIM];
#pragma unroll
        for (int n = 0; n < NB2; n++) {
#pragma unroll
            for (int j = 0; j < 32; j += 4) {
                float4 hv = *(const float4*)&hs[n][k0 + j];  // broadcast read
                acc[n] = fmaf(hv.x, w[j + 0], acc[n]);
                acc[n] = fmaf(hv.y, w[j + 1], acc[n]);
                acc[n] = fmaf(hv.z, w[j + 2], acc[n]);
                acc[n] = fmaf(hv.w, w[j + 3], acc[n]);
            }
        }
    }

    float asv = a2[t];
    float adv = a2[OUT_DIM + t];
#pragma unroll
    for (int n = 0; n < NB2; n++) {
        float z = acc[n];
        z2[(size_t)(n0 + n) * OUT_DIM + t] = z;
        float es = z * asv;
        float ed = z * adv;
#pragma unroll
        for (int off = 32; off >= 1; off >>= 1) {
            es += __shfl_xor(es, off);
            ed += __shfl_xor(ed, off);
        }
        if (t == 0) {
            es2[n0 + n] = es;
            ed2[n0 + n] = ed;
        }
    }
}

// ---------------- Layer 2 aggregation (final output) ----------------
// block = 64 threads (1 head x 64 lanes), one dst node per block

__global__ void agg2_kernel(const float* __restrict__ z2, const float* __restrict__ es2,
                            const float* __restrict__ ed2, const int* __restrict__ row_start,
                            const int* __restrict__ count, const int* __restrict__ esrc,
                            float* __restrict__ out) {
    int v = blockIdx.x, t = threadIdx.x;
    int beg = row_start[v], deg = count[v];
    float edv = ed2[v];
    float m = -1e30f;
    for (int j = 0; j < deg; j++) {
        int s = esrc[beg + j];
        float e = es2[s] + edv;
        e = e > 0.f ? e : 0.01f * e;
        m = fmaxf(m, e);
    }
    float l = 0.f, acc = 0.f;
    for (int j = 0; j < deg; j++) {
        int s = esrc[beg + j];
        float e = es2[s] + edv;
        e = e > 0.f ? e : 0.01f * e;
        float p = __expf(e - m);
        l += p;
        acc += p * z2[s * OUT_DIM + t];
    }
    out[v * OUT_DIM + t] = (deg > 0) ? acc / l : 0.f;
}

// ---------------- launch ----------------

extern "C" void kernel_launch(void* const* d_in, const int* in_sizes, int n_in,
                              void* d_out, int out_size, void* d_ws, size_t ws_size,
                              hipStream_t stream) {
    const float* h  = (const float*)d_in[0];
    const int* src  = (const int*)d_in[1];
    const int* dst  = (const int*)d_in[2];
    const float* W1 = (const float*)d_in[3];
    const float* a1 = (const float*)d_in[4];
    const float* W2 = (const float*)d_in[5];
    const float* a2 = (const float*)d_in[6];
    float* out = (float*)d_out;

    char* w = (char*)d_ws;
    size_t off = 0;
    auto alloc = [&](size_t bytes) {
        void* p = w + off;
        off = (off + bytes + 255) & ~(size_t)255;
        return p;
    };
    float* z1  = (float*)alloc((size_t)N_NODES * 128 * 4);
    float* es1 = (float*)alloc((size_t)N_NODES * HEADS * 4);
    float* ed1 = (float*)alloc((size_t)N_NODES * HEADS * 4);
    float* h1  = (float*)alloc((size_t)N_NODES * 128 * 4);
    float* z2  = (float*)alloc((size_t)N_NODES * OUT_DIM * 4);
    float* es2 = (float*)alloc((size_t)N_NODES * 4);
    float* ed2 = (float*)alloc((size_t)N_NODES * 4);
    int* count     = (int*)alloc((size_t)N_NODES * 4);
    int* row_start = (int*)alloc((size_t)N_NODES * 4);
    int* cursor    = (int*)alloc((size_t)N_NODES * 4);
    int* blocksum  = (int*)alloc((size_t)SCAN_BLOCKS * 4);
    int* bs2       = (int*)alloc((size_t)SCAN_BLOCKS * 4);
    int* esrc      = (int*)alloc((size_t)N_EDGES * 4);

    hipMemsetAsync(count, 0, (size_t)N_NODES * 4, stream);
    hist_kernel<<<(N_EDGES + 255) / 256, 256, 0, stream>>>(dst, count);
    scan1_kernel<<<SCAN_BLOCKS, 256, 0, stream>>>(count, row_start, blocksum);
    scan2_kernel<<<1, 64, 0, stream>>>(blocksum, bs2);
    scan3_kernel<<<SCAN_BLOCKS, 256, 0, stream>>>(row_start, bs2, cursor);
    scatter_kernel<<<(N_EDGES + 255) / 256, 256, 0, stream>>>(src, dst, cursor, esrc);

    proj1_kernel<<<N_NODES / NB1, 128, 0, stream>>>(h, W1, a1, z1, es1, ed1);
    agg1_kernel<<<N_NODES, 128, 0, stream>>>(z1, es1, ed1, row_start, count, esrc, h1);
    proj2_kernel<<<N_NODES / NB2, 64, 0, stream>>>(h1, W2, a2, z2, es2, ed2);
    agg2_kernel<<<N_NODES, 64, 0, stream>>>(z2, es2, ed2, row_start, count, esrc, out);
}

// Round 3
// 419.362 us; speedup vs baseline: 1.6473x; 1.4007x over previous
//
#include <hip/hip_runtime.h>
#include <hip/hip_bf16.h>
#include <math.h>

#define N_NODES 50000
#define N_EDGES 800000
#define IN_DIM 256
#define HID 32
#define HEADS 4
#define OUT_DIM 64

#define SCAN_CHUNK 1024
#define SCAN_BLOCKS ((N_NODES + SCAN_CHUNK - 1) / SCAN_CHUNK)  // 49

// ---------------- CSR build (by dst) ----------------

__global__ void hist_kernel(const int* __restrict__ dst, int* __restrict__ count) {
    int i = blockIdx.x * blockDim.x + threadIdx.x;
    if (i < N_EDGES) atomicAdd(&count[dst[i]], 1);
}

__global__ void scan1_kernel(const int* __restrict__ count, int* __restrict__ row_start,
                             int* __restrict__ blocksum) {
    __shared__ int sdata[256];
    int t = threadIdx.x;
    int base = blockIdx.x * SCAN_CHUNK + t * 4;
    int v[4];
    int s = 0;
#pragma unroll
    for (int j = 0; j < 4; j++) {
        int idx = base + j;
        int x = (idx < N_NODES) ? count[idx] : 0;
        v[j] = x;
        s += x;
    }
    sdata[t] = s;
    __syncthreads();
    for (int off = 1; off < 256; off <<= 1) {
        int u = (t >= off) ? sdata[t - off] : 0;
        __syncthreads();
        sdata[t] += u;
        __syncthreads();
    }
    int excl = sdata[t] - s;
#pragma unroll
    for (int j = 0; j < 4; j++) {
        int idx = base + j;
        if (idx < N_NODES) row_start[idx] = excl;
        excl += v[j];
    }
    if (t == 255) blocksum[blockIdx.x] = sdata[255];
}

__global__ void scan2_kernel(const int* __restrict__ blocksum, int* __restrict__ bs2) {
    int t = threadIdx.x;  // 64 threads, one wave
    int v = (t < SCAN_BLOCKS) ? blocksum[t] : 0;
    int orig = v;
#pragma unroll
    for (int off = 1; off < 64; off <<= 1) {
        int u = __shfl_up(v, off);
        if (t >= off) v += u;
    }
    if (t < SCAN_BLOCKS) bs2[t] = v - orig;
}

__global__ void scan3_kernel(int* __restrict__ row_start, const int* __restrict__ bs2,
                             int* __restrict__ cursor) {
    int t = threadIdx.x;
    int add = bs2[blockIdx.x];
    int base = blockIdx.x * SCAN_CHUNK + t * 4;
#pragma unroll
    for (int j = 0; j < 4; j++) {
        int idx = base + j;
        if (idx < N_NODES) {
            int r = row_start[idx] + add;
            row_start[idx] = r;
            cursor[idx] = r;
        }
    }
}

__global__ void scatter_kernel(const int* __restrict__ src, const int* __restrict__ dst,
                               int* __restrict__ cursor, int* __restrict__ esrc) {
    int i = blockIdx.x * blockDim.x + threadIdx.x;
    if (i < N_EDGES) {
        int d = dst[i];
        int pos = atomicAdd(&cursor[d], 1);
        esrc[pos] = src[i];
    }
}

// ---------------- Layer 1 projection: z1 = h @ W1, es1/ed1 logits ----------------

#define NB1 16

__global__ void __launch_bounds__(128) proj1_kernel(
        const float* __restrict__ h, const float* __restrict__ W1,
        const float* __restrict__ a1, float* __restrict__ z1,
        float* __restrict__ es1, float* __restrict__ ed1) {
    __shared__ __align__(16) float hs[NB1][IN_DIM];  // 16 KB
    int t = threadIdx.x;
    int n0 = blockIdx.x * NB1;
    {
        const float4* src4 = (const float4*)(h + (size_t)n0 * IN_DIM);
        float4* dst4 = (float4*)&hs[0][0];
        for (int i = t; i < NB1 * IN_DIM / 4; i += 128) dst4[i] = src4[i];
    }
    __syncthreads();

    int hd = t >> 5, o = t & 31;
    float acc[NB1];
#pragma unroll
    for (int n = 0; n < NB1; n++) acc[n] = 0.f;

    const float* Wbase = W1 + (size_t)hd * IN_DIM * HID + o;
#pragma unroll 1
    for (int k0 = 0; k0 < IN_DIM; k0 += 32) {
        float w[32];
#pragma unroll
        for (int j = 0; j < 32; j++) w[j] = Wbase[(size_t)(k0 + j) * HID];
#pragma unroll
        for (int n = 0; n < NB1; n++) {
#pragma unroll
            for (int j = 0; j < 32; j += 4) {
                float4 hv = *(const float4*)&hs[n][k0 + j];  // broadcast read
                acc[n] = fmaf(hv.x, w[j + 0], acc[n]);
                acc[n] = fmaf(hv.y, w[j + 1], acc[n]);
                acc[n] = fmaf(hv.z, w[j + 2], acc[n]);
                acc[n] = fmaf(hv.w, w[j + 3], acc[n]);
            }
        }
    }

    float asv = a1[hd * 2 * HID + o];
    float adv = a1[hd * 2 * HID + HID + o];
#pragma unroll
    for (int n = 0; n < NB1; n++) {
        float z = acc[n];
        z1[(size_t)(n0 + n) * 128 + t] = z;
        float es = z * asv;
        float ed = z * adv;
#pragma unroll
        for (int off = 16; off >= 1; off >>= 1) {
            es += __shfl_xor(es, off);
            ed += __shfl_xor(ed, off);
        }
        if (o == 0) {
            es1[(n0 + n) * HEADS + hd] = es;
            ed1[(n0 + n) * HEADS + hd] = ed;
        }
    }
}

// ---------------- Layer 1 aggregation + ELU ----------------
// block = 128 threads (4 heads x 32 lanes), one dst node per block.
// Single-pass online softmax; edge indices staged coalesced + shfl-distributed;
// gather loop unrolled x4 so 8 loads are in flight per latency window.

__device__ __forceinline__ float lrelu(float e) { return e > 0.f ? e : 0.01f * e; }

__global__ void agg1_kernel(const float* __restrict__ z1, const float* __restrict__ es1,
                            const float* __restrict__ ed1, const int* __restrict__ row_start,
                            const int* __restrict__ count, const int* __restrict__ esrc,
                            float* __restrict__ h1) {
    int v = blockIdx.x;
    int t = threadIdx.x;
    int hd = t >> 5, o = t & 31;
    int beg = row_start[v], deg = count[v];
    float edv = ed1[v * HEADS + hd];
    float m = -1e30f, l = 0.f, acc = 0.f;

    for (int j0 = 0; j0 < deg; j0 += 32) {
        int chunk = min(32, deg - j0);
        int sv = (j0 + o < deg) ? esrc[beg + j0 + o] : 0;  // coalesced
        int j = 0;
        for (; j + 4 <= chunk; j += 4) {
            int s0 = __shfl(sv, j + 0, 32);
            int s1 = __shfl(sv, j + 1, 32);
            int s2 = __shfl(sv, j + 2, 32);
            int s3 = __shfl(sv, j + 3, 32);
            // 8 independent loads issued before first use
            float e0 = es1[s0 * HEADS + hd];
            float e1 = es1[s1 * HEADS + hd];
            float e2 = es1[s2 * HEADS + hd];
            float e3 = es1[s3 * HEADS + hd];
            float g0 = z1[s0 * 128 + hd * HID + o];
            float g1 = z1[s1 * 128 + hd * HID + o];
            float g2 = z1[s2 * 128 + hd * HID + o];
            float g3 = z1[s3 * 128 + hd * HID + o];
            e0 = lrelu(e0 + edv);
            e1 = lrelu(e1 + edv);
            e2 = lrelu(e2 + edv);
            e3 = lrelu(e3 + edv);
            float mn = fmaxf(fmaxf(fmaxf(e0, e1), fmaxf(e2, e3)), m);
            float scale = __expf(m - mn);
            float p0 = __expf(e0 - mn);
            float p1 = __expf(e1 - mn);
            float p2 = __expf(e2 - mn);
            float p3 = __expf(e3 - mn);
            l = fmaf(l, scale, (p0 + p1) + (p2 + p3));
            acc = acc * scale;
            acc = fmaf(p0, g0, acc);
            acc = fmaf(p1, g1, acc);
            acc = fmaf(p2, g2, acc);
            acc = fmaf(p3, g3, acc);
            m = mn;
        }
        for (; j < chunk; j++) {
            int s = __shfl(sv, j, 32);
            float e = lrelu(es1[s * HEADS + hd] + edv);
            float g = z1[s * 128 + hd * HID + o];
            float mn = fmaxf(e, m);
            float scale = __expf(m - mn);
            float p = __expf(e - mn);
            l = fmaf(l, scale, p);
            acc = fmaf(p, g, acc * scale);
            m = mn;
        }
    }

    float r = (deg > 0) ? acc / l : 0.f;
    r = r > 0.f ? r : expm1f(r);  // elu
    h1[v * 128 + t] = r;
}

// ---------------- Layer 2 projection: z2 = h1 @ W2, es2/ed2 ----------------

#define NB2 16

__global__ void __launch_bounds__(64) proj2_kernel(
        const float* __restrict__ h1, const float* __restrict__ W2,
        const float* __restrict__ a2, float* __restrict__ z2,
        float* __restrict__ es2, float* __restrict__ ed2) {
    __shared__ __align__(16) float hs[NB2][128];  // 8 KB
    int t = threadIdx.x;  // 0..63, one wave
    int n0 = blockIdx.x * NB2;
    {
        const float4* src4 = (const float4*)(h1 + (size_t)n0 * 128);
        float4* dst4 = (float4*)&hs[0][0];
        for (int i = t; i < NB2 * 128 / 4; i += 64) dst4[i] = src4[i];
    }
    __syncthreads();

    float acc[NB2];
#pragma unroll
    for (int n = 0; n < NB2; n++) acc[n] = 0.f;

    const float* Wbase = W2 + t;
#pragma unroll 1
    for (int k0 = 0; k0 < 128; k0 += 32) {
        float w[32];
#pragma unroll
        for (int j = 0; j < 32; j++) w[j] = Wbase[(size_t)(k0 + j) * OUT_DIM];
#pragma unroll
        for (int n = 0; n < NB2; n++) {
#pragma unroll
            for (int j = 0; j < 32; j += 4) {
                float4 hv = *(const float4*)&hs[n][k0 + j];  // broadcast read
                acc[n] = fmaf(hv.x, w[j + 0], acc[n]);
                acc[n] = fmaf(hv.y, w[j + 1], acc[n]);
                acc[n] = fmaf(hv.z, w[j + 2], acc[n]);
                acc[n] = fmaf(hv.w, w[j + 3], acc[n]);
            }
        }
    }

    float asv = a2[t];
    float adv = a2[OUT_DIM + t];
#pragma unroll
    for (int n = 0; n < NB2; n++) {
        float z = acc[n];
        z2[(size_t)(n0 + n) * OUT_DIM + t] = z;
        float es = z * asv;
        float ed = z * adv;
#pragma unroll
        for (int off = 32; off >= 1; off >>= 1) {
            es += __shfl_xor(es, off);
            ed += __shfl_xor(ed, off);
        }
        if (t == 0) {
            es2[n0 + n] = es;
            ed2[n0 + n] = ed;
        }
    }
}

// ---------------- Layer 2 aggregation (final output) ----------------
// block = 64 threads, one dst node per block; same online-softmax + x4 unroll.

__global__ void agg2_kernel(const float* __restrict__ z2, const float* __restrict__ es2,
                            const float* __restrict__ ed2, const int* __restrict__ row_start,
                            const int* __restrict__ count, const int* __restrict__ esrc,
                            float* __restrict__ out) {
    int v = blockIdx.x, t = threadIdx.x;
    int beg = row_start[v], deg = count[v];
    float edv = ed2[v];
    float m = -1e30f, l = 0.f, acc = 0.f;

    for (int j0 = 0; j0 < deg; j0 += 64) {
        int chunk = min(64, deg - j0);
        int sv = (j0 + t < deg) ? esrc[beg + j0 + t] : 0;  // coalesced
        int j = 0;
        for (; j + 4 <= chunk; j += 4) {
            int s0 = __shfl(sv, j + 0);
            int s1 = __shfl(sv, j + 1);
            int s2 = __shfl(sv, j + 2);
            int s3 = __shfl(sv, j + 3);
            float e0 = es2[s0];
            float e1 = es2[s1];
            float e2 = es2[s2];
            float e3 = es2[s3];
            float g0 = z2[s0 * OUT_DIM + t];
            float g1 = z2[s1 * OUT_DIM + t];
            float g2 = z2[s2 * OUT_DIM + t];
            float g3 = z2[s3 * OUT_DIM + t];
            e0 = lrelu(e0 + edv);
            e1 = lrelu(e1 + edv);
            e2 = lrelu(e2 + edv);
            e3 = lrelu(e3 + edv);
            float mn = fmaxf(fmaxf(fmaxf(e0, e1), fmaxf(e2, e3)), m);
            float scale = __expf(m - mn);
            float p0 = __expf(e0 - mn);
            float p1 = __expf(e1 - mn);
            float p2 = __expf(e2 - mn);
            float p3 = __expf(e3 - mn);
            l = fmaf(l, scale, (p0 + p1) + (p2 + p3));
            acc = acc * scale;
            acc = fmaf(p0, g0, acc);
            acc = fmaf(p1, g1, acc);
            acc = fmaf(p2, g2, acc);
            acc = fmaf(p3, g3, acc);
            m = mn;
        }
        for (; j < chunk; j++) {
            int s = __shfl(sv, j);
            float e = lrelu(es2[s] + edv);
            float g = z2[s * OUT_DIM + t];
            float mn = fmaxf(e, m);
            float scale = __expf(m - mn);
            float p = __expf(e - mn);
            l = fmaf(l, scale, p);
            acc = fmaf(p, g, acc * scale);
            m = mn;
        }
    }

    out[v * OUT_DIM + t] = (deg > 0) ? acc / l : 0.f;
}

// ---------------- launch ----------------

extern "C" void kernel_launch(void* const* d_in, const int* in_sizes, int n_in,
                              void* d_out, int out_size, void* d_ws, size_t ws_size,
                              hipStream_t stream) {
    const float* h  = (const float*)d_in[0];
    const int* src  = (const int*)d_in[1];
    const int* dst  = (const int*)d_in[2];
    const float* W1 = (const float*)d_in[3];
    const float* a1 = (const float*)d_in[4];
    const float* W2 = (const float*)d_in[5];
    const float* a2 = (const float*)d_in[6];
    float* out = (float*)d_out;

    char* w = (char*)d_ws;
    size_t off = 0;
    auto alloc = [&](size_t bytes) {
        void* p = w + off;
        off = (off + bytes + 255) & ~(size_t)255;
        return p;
    };
    float* z1  = (float*)alloc((size_t)N_NODES * 128 * 4);
    float* es1 = (float*)alloc((size_t)N_NODES * HEADS * 4);
    float* ed1 = (float*)alloc((size_t)N_NODES * HEADS * 4);
    float* h1  = (float*)alloc((size_t)N_NODES * 128 * 4);
    float* z2  = (float*)alloc((size_t)N_NODES * OUT_DIM * 4);
    float* es2 = (float*)alloc((size_t)N_NODES * 4);
    float* ed2 = (float*)alloc((size_t)N_NODES * 4);
    int* count     = (int*)alloc((size_t)N_NODES * 4);
    int* row_start = (int*)alloc((size_t)N_NODES * 4);
    int* cursor    = (int*)alloc((size_t)N_NODES * 4);
    int* blocksum  = (int*)alloc((size_t)SCAN_BLOCKS * 4);
    int* bs2       = (int*)alloc((size_t)SCAN_BLOCKS * 4);
    int* esrc      = (int*)alloc((size_t)N_EDGES * 4);

    hipMemsetAsync(count, 0, (size_t)N_NODES * 4, stream);
    hist_kernel<<<(N_EDGES + 255) / 256, 256, 0, stream>>>(dst, count);
    scan1_kernel<<<SCAN_BLOCKS, 256, 0, stream>>>(count, row_start, blocksum);
    scan2_kernel<<<1, 64, 0, stream>>>(blocksum, bs2);
    scan3_kernel<<<SCAN_BLOCKS, 256, 0, stream>>>(row_start, bs2, cursor);
    scatter_kernel<<<(N_EDGES + 255) / 256, 256, 0, stream>>>(src, dst, cursor, esrc);

    proj1_kernel<<<N_NODES / NB1, 128, 0, stream>>>(h, W1, a1, z1, es1, ed1);
    agg1_kernel<<<N_NODES, 128, 0, stream>>>(z1, es1, ed1, row_start, count, esrc, h1);
    proj2_kernel<<<N_NODES / NB2, 64, 0, stream>>>(h1, W2, a2, z2, es2, ed2);
    agg2_kernel<<<N_NODES, 64, 0, stream>>>(z2, es2, ed2, row_start, count, esrc, out);
}

// Round 4
// 330.234 us; speedup vs baseline: 2.0919x; 1.2699x over previous
//
#include <hip/hip_runtime.h>
#include <hip/hip_bf16.h>
#include <math.h>

#define N_NODES 50000
#define N_EDGES 800000
#define IN_DIM 256
#define HID 32
#define HEADS 4
#define OUT_DIM 64

#define SCAN_CHUNK 1024
#define SCAN_BLOCKS ((N_NODES + SCAN_CHUNK - 1) / SCAN_CHUNK)  // 49

typedef __attribute__((ext_vector_type(8))) short bf16x8;
typedef __attribute__((ext_vector_type(4))) float f32x4;

// ---------------- CSR build (by dst) ----------------

__global__ void hist_kernel(const int* __restrict__ dst, int* __restrict__ count) {
    int i = blockIdx.x * blockDim.x + threadIdx.x;
    if (i < N_EDGES) atomicAdd(&count[dst[i]], 1);
}

__global__ void scan1_kernel(const int* __restrict__ count, int* __restrict__ row_start,
                             int* __restrict__ blocksum) {
    __shared__ int sdata[256];
    int t = threadIdx.x;
    int base = blockIdx.x * SCAN_CHUNK + t * 4;
    int v[4];
    int s = 0;
#pragma unroll
    for (int j = 0; j < 4; j++) {
        int idx = base + j;
        int x = (idx < N_NODES) ? count[idx] : 0;
        v[j] = x;
        s += x;
    }
    sdata[t] = s;
    __syncthreads();
    for (int off = 1; off < 256; off <<= 1) {
        int u = (t >= off) ? sdata[t - off] : 0;
        __syncthreads();
        sdata[t] += u;
        __syncthreads();
    }
    int excl = sdata[t] - s;
#pragma unroll
    for (int j = 0; j < 4; j++) {
        int idx = base + j;
        if (idx < N_NODES) row_start[idx] = excl;
        excl += v[j];
    }
    if (t == 255) blocksum[blockIdx.x] = sdata[255];
}

__global__ void scan2_kernel(const int* __restrict__ blocksum, int* __restrict__ bs2) {
    int t = threadIdx.x;  // 64 threads, one wave
    int v = (t < SCAN_BLOCKS) ? blocksum[t] : 0;
    int orig = v;
#pragma unroll
    for (int off = 1; off < 64; off <<= 1) {
        int u = __shfl_up(v, off);
        if (t >= off) v += u;
    }
    if (t < SCAN_BLOCKS) bs2[t] = v - orig;
}

__global__ void scan3_kernel(int* __restrict__ row_start, const int* __restrict__ bs2,
                             int* __restrict__ cursor) {
    int t = threadIdx.x;
    int add = bs2[blockIdx.x];
    int base = blockIdx.x * SCAN_CHUNK + t * 4;
#pragma unroll
    for (int j = 0; j < 4; j++) {
        int idx = base + j;
        if (idx < N_NODES) {
            int r = row_start[idx] + add;
            row_start[idx] = r;
            cursor[idx] = r;
        }
    }
}

__global__ void scatter_kernel(const int* __restrict__ src, const int* __restrict__ dst,
                               int* __restrict__ cursor, int* __restrict__ esrc) {
    int i = blockIdx.x * blockDim.x + threadIdx.x;
    if (i < N_EDGES) {
        int d = dst[i];
        int pos = atomicAdd(&cursor[d], 1);
        esrc[pos] = src[i];
    }
}

// ---------------- bf16 split helpers ----------------

__device__ __forceinline__ void splitf(float x, short& hi, short& lo) {
    unsigned u = __float_as_uint(x);
    unsigned short h = (unsigned short)(u >> 16);          // truncate to bf16
    float hf = __uint_as_float(((unsigned)h) << 16);
    float l = x - hf;                                      // residual
    unsigned short lb = (unsigned short)(__float_as_uint(l) >> 16);
    hi = (short)h;
    lo = (short)lb;
}

// ---------------- B-fragment precompute ----------------
// Layer 1: B is 256x144 (cols 0..127 = W1 as [k][c], c=head*32+o;
// cols 128..131 = W1·a_s per head (es), 132..135 = W1·a_d per head (ed); 136..143 = 0).
// Packed fragment layout for mfma_f32_16x16x32_bf16 B operand
// (n = lane&15, k = (lane>>4)*8 + j):  idx = ((s*9 + nt)*64 + L)*8 + j

__global__ void prepB1_kernel(const float* __restrict__ W1, const float* __restrict__ a1,
                              unsigned short* __restrict__ Bh, unsigned short* __restrict__ Bl) {
    int k = blockIdx.x;       // 0..255
    int c = threadIdx.x;      // 0..159, use c<144
    if (c >= 144) return;
    float val = 0.f;
    if (c < 128) {
        val = W1[(size_t)(c >> 5) * IN_DIM * HID + (size_t)k * HID + (c & 31)];
    } else if (c < 136) {
        int j = c - 128;
        int hd = (j < 4) ? j : (j - 4);
        int off = (j < 4) ? 0 : HID;
        const float* Wp = W1 + (size_t)hd * IN_DIM * HID + (size_t)k * HID;
        const float* ap = a1 + hd * 2 * HID + off;
        float s = 0.f;
        for (int o = 0; o < HID; o++) s += Wp[o] * ap[o];
        val = s;
    }
    short hi, lo;
    splitf(val, hi, lo);
    int s_ = k >> 5, q = (k >> 3) & 3, j8 = k & 7;
    int nt = c >> 4, L = q * 16 + (c & 15);
    size_t idx = (((size_t)s_ * 9 + nt) * 64 + L) * 8 + j8;
    Bh[idx] = (unsigned short)hi;
    Bl[idx] = (unsigned short)lo;
}

// Layer 2: B is 128x80 (cols 0..63 = W2[k][c]; 64 = W2·a_s; 65 = W2·a_d; 66..79 = 0)
// idx = ((s*5 + nt)*64 + L)*8 + j

__global__ void prepB2_kernel(const float* __restrict__ W2, const float* __restrict__ a2,
                              unsigned short* __restrict__ Bh, unsigned short* __restrict__ Bl) {
    int k = blockIdx.x;       // 0..127
    int c = threadIdx.x;      // 0..79
    if (c >= 80) return;
    float val = 0.f;
    if (c < 64) {
        val = W2[(size_t)k * OUT_DIM + c];
    } else if (c < 66) {
        const float* ap = a2 + (c - 64) * OUT_DIM;
        const float* Wp = W2 + (size_t)k * OUT_DIM;
        float s = 0.f;
        for (int o = 0; o < OUT_DIM; o++) s += Wp[o] * ap[o];
        val = s;
    }
    short hi, lo;
    splitf(val, hi, lo);
    int s_ = k >> 5, q = (k >> 3) & 3, j8 = k & 7;
    int nt = c >> 4, L = q * 16 + (c & 15);
    size_t idx = (((size_t)s_ * 5 + nt) * 64 + L) * 8 + j8;
    Bh[idx] = (unsigned short)hi;
    Bl[idx] = (unsigned short)lo;
}

// ---------------- Layer 1 projection via MFMA (split-bf16, ~fp32 accurate) ----------
// Block = 256 thr = 4 waves; M=64 nodes/block, N=144 (9 tiles), K=256 (8 steps).
// D = Ahi·Bhi + Alo·Bhi + Ahi·Blo accumulated fp32 in MFMA.

__global__ void __launch_bounds__(256) proj1_mfma(
        const float* __restrict__ h, const unsigned short* __restrict__ Bh,
        const unsigned short* __restrict__ Bl, float* __restrict__ z1,
        float* __restrict__ es1, float* __restrict__ ed1) {
    int tid = threadIdx.x;
    int wave = tid >> 6;
    int L = tid & 63;
    int q = L >> 4, L15 = L & 15;
    int n0 = blockIdx.x * 64 + wave * 16;

    int rowA = n0 + L15;                      // A-operand row for this lane
    int rrA = rowA < N_NODES ? rowA : N_NODES - 1;
    const float* hrow = h + (size_t)rrA * IN_DIM + q * 8;

    f32x4 acc[9];
#pragma unroll
    for (int nt = 0; nt < 9; nt++) acc[nt] = (f32x4)(0.f);

    float4 x0 = *(const float4*)(hrow);
    float4 x1 = *(const float4*)(hrow + 4);

#pragma unroll
    for (int s = 0; s < 8; s++) {
        // prefetch next A chunk
        int sn = (s < 7) ? s + 1 : 7;
        float4 p0 = *(const float4*)(hrow + sn * 32);
        float4 p1 = *(const float4*)(hrow + sn * 32 + 4);

        float xs[8] = {x0.x, x0.y, x0.z, x0.w, x1.x, x1.y, x1.z, x1.w};
        bf16x8 ah, al;
#pragma unroll
        for (int j = 0; j < 8; j++) {
            short hi, lo;
            splitf(xs[j], hi, lo);
            ah[j] = hi;
            al[j] = lo;
        }

        const bf16x8* bhp = (const bf16x8*)(Bh + ((size_t)s * 9 * 64) * 8 + (size_t)L * 8);
        const bf16x8* blp = (const bf16x8*)(Bl + ((size_t)s * 9 * 64) * 8 + (size_t)L * 8);
#pragma unroll
        for (int nt = 0; nt < 9; nt++) {
            bf16x8 bh = bhp[nt * 64];
            bf16x8 bl = blp[nt * 64];
            acc[nt] = __builtin_amdgcn_mfma_f32_16x16x32_bf16(ah, bh, acc[nt], 0, 0, 0);
            acc[nt] = __builtin_amdgcn_mfma_f32_16x16x32_bf16(al, bh, acc[nt], 0, 0, 0);
            acc[nt] = __builtin_amdgcn_mfma_f32_16x16x32_bf16(ah, bl, acc[nt], 0, 0, 0);
        }
        x0 = p0;
        x1 = p1;
    }

    // C/D layout: col = L15, row = q*4 + r
#pragma unroll
    for (int r = 0; r < 4; r++) {
        int rowc = n0 + q * 4 + r;
        if (rowc < N_NODES) {
#pragma unroll
            for (int nt = 0; nt < 8; nt++)
                z1[(size_t)rowc * 128 + nt * 16 + L15] = acc[nt][r];
            if (L15 < 4) es1[rowc * HEADS + L15] = acc[8][r];
            else if (L15 < 8) ed1[rowc * HEADS + (L15 - 4)] = acc[8][r];
        }
    }
}

// ---------------- Layer 2 projection via MFMA ----------------
// M=64, N=80 (5 tiles), K=128 (4 steps)

__global__ void __launch_bounds__(256) proj2_mfma(
        const float* __restrict__ h1, const unsigned short* __restrict__ Bh,
        const unsigned short* __restrict__ Bl, float* __restrict__ z2,
        float* __restrict__ es2, float* __restrict__ ed2) {
    int tid = threadIdx.x;
    int wave = tid >> 6;
    int L = tid & 63;
    int q = L >> 4, L15 = L & 15;
    int n0 = blockIdx.x * 64 + wave * 16;

    int rowA = n0 + L15;
    int rrA = rowA < N_NODES ? rowA : N_NODES - 1;
    const float* hrow = h1 + (size_t)rrA * 128 + q * 8;

    f32x4 acc[5];
#pragma unroll
    for (int nt = 0; nt < 5; nt++) acc[nt] = (f32x4)(0.f);

    float4 x0 = *(const float4*)(hrow);
    float4 x1 = *(const float4*)(hrow + 4);

#pragma unroll
    for (int s = 0; s < 4; s++) {
        int sn = (s < 3) ? s + 1 : 3;
        float4 p0 = *(const float4*)(hrow + sn * 32);
        float4 p1 = *(const float4*)(hrow + sn * 32 + 4);

        float xs[8] = {x0.x, x0.y, x0.z, x0.w, x1.x, x1.y, x1.z, x1.w};
        bf16x8 ah, al;
#pragma unroll
        for (int j = 0; j < 8; j++) {
            short hi, lo;
            splitf(xs[j], hi, lo);
            ah[j] = hi;
            al[j] = lo;
        }

        const bf16x8* bhp = (const bf16x8*)(Bh + ((size_t)s * 5 * 64) * 8 + (size_t)L * 8);
        const bf16x8* blp = (const bf16x8*)(Bl + ((size_t)s * 5 * 64) * 8 + (size_t)L * 8);
#pragma unroll
        for (int nt = 0; nt < 5; nt++) {
            bf16x8 bh = bhp[nt * 64];
            bf16x8 bl = blp[nt * 64];
            acc[nt] = __builtin_amdgcn_mfma_f32_16x16x32_bf16(ah, bh, acc[nt], 0, 0, 0);
            acc[nt] = __builtin_amdgcn_mfma_f32_16x16x32_bf16(al, bh, acc[nt], 0, 0, 0);
            acc[nt] = __builtin_amdgcn_mfma_f32_16x16x32_bf16(ah, bl, acc[nt], 0, 0, 0);
        }
        x0 = p0;
        x1 = p1;
    }

#pragma unroll
    for (int r = 0; r < 4; r++) {
        int rowc = n0 + q * 4 + r;
        if (rowc < N_NODES) {
#pragma unroll
            for (int nt = 0; nt < 4; nt++)
                z2[(size_t)rowc * OUT_DIM + nt * 16 + L15] = acc[nt][r];
            if (L15 == 0) es2[rowc] = acc[4][r];
            else if (L15 == 1) ed2[rowc] = acc[4][r];
        }
    }
}

// ---------------- Layer 1 aggregation + ELU ----------------

__device__ __forceinline__ float lrelu(float e) { return e > 0.f ? e : 0.01f * e; }

__global__ void agg1_kernel(const float* __restrict__ z1, const float* __restrict__ es1,
                            const float* __restrict__ ed1, const int* __restrict__ row_start,
                            const int* __restrict__ count, const int* __restrict__ esrc,
                            float* __restrict__ h1) {
    int v = blockIdx.x;
    int t = threadIdx.x;
    int hd = t >> 5, o = t & 31;
    int beg = row_start[v], deg = count[v];
    float edv = ed1[v * HEADS + hd];
    float m = -1e30f, l = 0.f, acc = 0.f;

    for (int j0 = 0; j0 < deg; j0 += 32) {
        int chunk = min(32, deg - j0);
        int sv = (j0 + o < deg) ? esrc[beg + j0 + o] : 0;  // coalesced
        int j = 0;
        for (; j + 4 <= chunk; j += 4) {
            int s0 = __shfl(sv, j + 0, 32);
            int s1 = __shfl(sv, j + 1, 32);
            int s2 = __shfl(sv, j + 2, 32);
            int s3 = __shfl(sv, j + 3, 32);
            float e0 = es1[s0 * HEADS + hd];
            float e1 = es1[s1 * HEADS + hd];
            float e2 = es1[s2 * HEADS + hd];
            float e3 = es1[s3 * HEADS + hd];
            float g0 = z1[s0 * 128 + hd * HID + o];
            float g1 = z1[s1 * 128 + hd * HID + o];
            float g2 = z1[s2 * 128 + hd * HID + o];
            float g3 = z1[s3 * 128 + hd * HID + o];
            e0 = lrelu(e0 + edv);
            e1 = lrelu(e1 + edv);
            e2 = lrelu(e2 + edv);
            e3 = lrelu(e3 + edv);
            float mn = fmaxf(fmaxf(fmaxf(e0, e1), fmaxf(e2, e3)), m);
            float scale = __expf(m - mn);
            float p0 = __expf(e0 - mn);
            float p1 = __expf(e1 - mn);
            float p2 = __expf(e2 - mn);
            float p3 = __expf(e3 - mn);
            l = fmaf(l, scale, (p0 + p1) + (p2 + p3));
            acc = acc * scale;
            acc = fmaf(p0, g0, acc);
            acc = fmaf(p1, g1, acc);
            acc = fmaf(p2, g2, acc);
            acc = fmaf(p3, g3, acc);
            m = mn;
        }
        for (; j < chunk; j++) {
            int s = __shfl(sv, j, 32);
            float e = lrelu(es1[s * HEADS + hd] + edv);
            float g = z1[s * 128 + hd * HID + o];
            float mn = fmaxf(e, m);
            float scale = __expf(m - mn);
            float p = __expf(e - mn);
            l = fmaf(l, scale, p);
            acc = fmaf(p, g, acc * scale);
            m = mn;
        }
    }

    float r = (deg > 0) ? acc / l : 0.f;
    r = r > 0.f ? r : expm1f(r);  // elu
    h1[v * 128 + t] = r;
}

// ---------------- Layer 2 aggregation (final output) ----------------

__global__ void agg2_kernel(const float* __restrict__ z2, const float* __restrict__ es2,
                            const float* __restrict__ ed2, const int* __restrict__ row_start,
                            const int* __restrict__ count, const int* __restrict__ esrc,
                            float* __restrict__ out) {
    int v = blockIdx.x, t = threadIdx.x;
    int beg = row_start[v], deg = count[v];
    float edv = ed2[v];
    float m = -1e30f, l = 0.f, acc = 0.f;

    for (int j0 = 0; j0 < deg; j0 += 64) {
        int chunk = min(64, deg - j0);
        int sv = (j0 + t < deg) ? esrc[beg + j0 + t] : 0;  // coalesced
        int j = 0;
        for (; j + 4 <= chunk; j += 4) {
            int s0 = __shfl(sv, j + 0);
            int s1 = __shfl(sv, j + 1);
            int s2 = __shfl(sv, j + 2);
            int s3 = __shfl(sv, j + 3);
            float e0 = es2[s0];
            float e1 = es2[s1];
            float e2 = es2[s2];
            float e3 = es2[s3];
            float g0 = z2[s0 * OUT_DIM + t];
            float g1 = z2[s1 * OUT_DIM + t];
            float g2 = z2[s2 * OUT_DIM + t];
            float g3 = z2[s3 * OUT_DIM + t];
            e0 = lrelu(e0 + edv);
            e1 = lrelu(e1 + edv);
            e2 = lrelu(e2 + edv);
            e3 = lrelu(e3 + edv);
            float mn = fmaxf(fmaxf(fmaxf(e0, e1), fmaxf(e2, e3)), m);
            float scale = __expf(m - mn);
            float p0 = __expf(e0 - mn);
            float p1 = __expf(e1 - mn);
            float p2 = __expf(e2 - mn);
            float p3 = __expf(e3 - mn);
            l = fmaf(l, scale, (p0 + p1) + (p2 + p3));
            acc = acc * scale;
            acc = fmaf(p0, g0, acc);
            acc = fmaf(p1, g1, acc);
            acc = fmaf(p2, g2, acc);
            acc = fmaf(p3, g3, acc);
            m = mn;
        }
        for (; j < chunk; j++) {
            int s = __shfl(sv, j);
            float e = lrelu(es2[s] + edv);
            float g = z2[s * OUT_DIM + t];
            float mn = fmaxf(e, m);
            float scale = __expf(m - mn);
            float p = __expf(e - mn);
            l = fmaf(l, scale, p);
            acc = fmaf(p, g, acc * scale);
            m = mn;
        }
    }

    out[v * OUT_DIM + t] = (deg > 0) ? acc / l : 0.f;
}

// ---------------- launch ----------------

extern "C" void kernel_launch(void* const* d_in, const int* in_sizes, int n_in,
                              void* d_out, int out_size, void* d_ws, size_t ws_size,
                              hipStream_t stream) {
    const float* h  = (const float*)d_in[0];
    const int* src  = (const int*)d_in[1];
    const int* dst  = (const int*)d_in[2];
    const float* W1 = (const float*)d_in[3];
    const float* a1 = (const float*)d_in[4];
    const float* W2 = (const float*)d_in[5];
    const float* a2 = (const float*)d_in[6];
    float* out = (float*)d_out;

    char* w = (char*)d_ws;
    size_t off = 0;
    auto alloc = [&](size_t bytes) {
        void* p = w + off;
        off = (off + bytes + 255) & ~(size_t)255;
        return p;
    };
    float* z1  = (float*)alloc((size_t)N_NODES * 128 * 4);
    float* es1 = (float*)alloc((size_t)N_NODES * HEADS * 4);
    float* ed1 = (float*)alloc((size_t)N_NODES * HEADS * 4);
    float* h1  = (float*)alloc((size_t)N_NODES * 128 * 4);
    float* z2  = (float*)alloc((size_t)N_NODES * OUT_DIM * 4);
    float* es2 = (float*)alloc((size_t)N_NODES * 4);
    float* ed2 = (float*)alloc((size_t)N_NODES * 4);
    int* count     = (int*)alloc((size_t)N_NODES * 4);
    int* row_start = (int*)alloc((size_t)N_NODES * 4);
    int* cursor    = (int*)alloc((size_t)N_NODES * 4);
    int* blocksum  = (int*)alloc((size_t)SCAN_BLOCKS * 4);
    int* bs2       = (int*)alloc((size_t)SCAN_BLOCKS * 4);
    int* esrc      = (int*)alloc((size_t)N_EDGES * 4);
    unsigned short* Bf1h = (unsigned short*)alloc((size_t)8 * 9 * 64 * 8 * 2);
    unsigned short* Bf1l = (unsigned short*)alloc((size_t)8 * 9 * 64 * 8 * 2);
    unsigned short* Bf2h = (unsigned short*)alloc((size_t)4 * 5 * 64 * 8 * 2);
    unsigned short* Bf2l = (unsigned short*)alloc((size_t)4 * 5 * 64 * 8 * 2);

    prepB1_kernel<<<256, 160, 0, stream>>>(W1, a1, Bf1h, Bf1l);
    prepB2_kernel<<<128, 80, 0, stream>>>(W2, a2, Bf2h, Bf2l);

    hipMemsetAsync(count, 0, (size_t)N_NODES * 4, stream);
    hist_kernel<<<(N_EDGES + 255) / 256, 256, 0, stream>>>(dst, count);
    scan1_kernel<<<SCAN_BLOCKS, 256, 0, stream>>>(count, row_start, blocksum);
    scan2_kernel<<<1, 64, 0, stream>>>(blocksum, bs2);
    scan3_kernel<<<SCAN_BLOCKS, 256, 0, stream>>>(row_start, bs2, cursor);
    scatter_kernel<<<(N_EDGES + 255) / 256, 256, 0, stream>>>(src, dst, cursor, esrc);

    const int MBLK = (N_NODES + 63) / 64;  // 782
    proj1_mfma<<<MBLK, 256, 0, stream>>>(h, Bf1h, Bf1l, z1, es1, ed1);
    agg1_kernel<<<N_NODES, 128, 0, stream>>>(z1, es1, ed1, row_start, count, esrc, h1);
    proj2_mfma<<<MBLK, 256, 0, stream>>>(h1, Bf2h, Bf2l, z2, es2, ed2);
    agg2_kernel<<<N_NODES, 64, 0, stream>>>(z2, es2, ed2, row_start, count, esrc, out);
}